// Round 11
// baseline (1614.629 us; speedup 1.0000x reference)
//
#include <hip/hip_runtime.h>

// WaveNet (nsynth batch-folding) on MI355X — persistent kernel, v11.
// Stream identity: batch-folding dilation == dilated conv over one 8192-sample
// stream, j = l*2 + n; fold-d taps at j +- 2d, zero-pad at stream ends.
//
// v11 = v5's proven schedule with M=64 samples/block, 128 blocks (1 per 2 CUs).
// Rationale: v5 is L2-BW-bound on weight re-reads (each of 256 CUs pulls the
// full 1MB layer weights -> 32MB/XCD/layer at ~1TB/s effective = the measured
// 32us/layer). Halving the block count halves per-XCD weight traffic; MFMA
// per CU doubles but stays far below the memory time. B chunks shrink to
// 32 rows x 32K (2KB, 2 DMA loads, ring-3, vmcnt(4) depth-2) so LDS stays at
// the proven 144KB (A = 3 taps x 64 rows = 96KB). H/S fp32 masters in
// registers (state[4][4]); tap1 center written by epilogue; 1 grid barrier
// per layer; cross-barrier weight prefetch.

#define TS 8192
#define NL 30
#define NBLK 128

typedef __attribute__((ext_vector_type(8))) short bf16x8;
typedef __attribute__((ext_vector_type(4))) float f32x4;

__device__ __forceinline__ unsigned short f2bf(float f) {
    union { float f; unsigned int u; } v; v.f = f;
    unsigned int u = v.u;
    u += 0x7fffu + ((u >> 16) & 1u);   // RNE
    return (unsigned short)(u >> 16);
}

__device__ __forceinline__ void gload_lds16(const void* g, void* l) {
    __builtin_amdgcn_global_load_lds(
        (const __attribute__((address_space(1))) void*)g,
        (__attribute__((address_space(3))) void*)l, 16, 0, 0);
}

#define VMW4()  asm volatile("s_waitcnt vmcnt(4)" ::: "memory")
#define VMW2()  asm volatile("s_waitcnt vmcnt(2)" ::: "memory")
#define VMW0()  asm volatile("s_waitcnt vmcnt(0)" ::: "memory")
#define LGKM0() asm volatile("s_waitcnt lgkmcnt(0)" ::: "memory")
#define SBAR()  __builtin_amdgcn_s_barrier()
#define MFMA16(a, b, c) __builtin_amdgcn_mfma_f32_16x16x32_bf16((a), (b), (c), 0, 0, 0)

__device__ __forceinline__ int swz_jb(int bid) {   // 128 blocks, XCD-chunked
    return ((bid & 7) << 4) | (bid >> 3);          // XCD x owns samples [x*1024,..)
}

// ---------------------------------------------------------------------------
// Weight prep (unchanged layout):
// Wgf[k][t][o][ci], o in [0,512): 0..255 gate, 256..511 feat (tap t split out)
// Wts[k][o][ci],    o in [0,512): 0..255 thru, 256..511 skip
// ---------------------------------------------------------------------------
__global__ void prep_weights_kernel(
    const float* __restrict__ gw, const float* __restrict__ fw,
    const float* __restrict__ tw, const float* __restrict__ sw,
    const float* __restrict__ iw, const float* __restrict__ fnw,
    unsigned short* __restrict__ Wgf, unsigned short* __restrict__ Wts,
    unsigned short* __restrict__ Wib, unsigned short* __restrict__ Wfb)
{
    const int idx = blockIdx.x * blockDim.x + threadIdx.x;
    const int stride = gridDim.x * blockDim.x;
    const int n_gf = NL * 3 * 512 * 256;
    for (int i = idx; i < n_gf; i += stride) {
        int ci = i & 255;
        int o  = (i >> 8) & 511;
        int r  = i >> 17;      // k*3 + t
        int t  = r % 3;
        int k  = r / 3;
        float v = (o < 256) ? gw[((k * 256 + o) * 256 + ci) * 3 + t]
                            : fw[((k * 256 + (o - 256)) * 256 + ci) * 3 + t];
        Wgf[i] = f2bf(v);
    }
    const int n_ts = NL * 512 * 256;
    for (int i = idx; i < n_ts; i += stride) {
        int ci = i & 255;
        int o  = (i >> 8) & 511;
        int k  = i >> 17;
        float v = (o < 256) ? tw[(k * 256 + o) * 256 + ci]
                            : sw[(k * 256 + (o - 256)) * 256 + ci];
        Wts[i] = f2bf(v);
    }
    for (int i = idx; i < 256 * 256; i += stride) Wib[i] = f2bf(iw[i]);
    for (int i = idx; i < 256 * 256; i += stride) Wfb[i] = f2bf(fnw[i]);
}

// ---------------------------------------------------------------------------
__device__ __forceinline__ void grid_barrier(unsigned* cnt, unsigned target, int tid) {
    __syncthreads();
    if (tid == 0) {
        __hip_atomic_fetch_add(cnt, 1u, __ATOMIC_RELEASE, __HIP_MEMORY_SCOPE_AGENT);
        while (__hip_atomic_load(cnt, __ATOMIC_RELAXED, __HIP_MEMORY_SCOPE_AGENT) < target)
            __builtin_amdgcn_s_sleep(2);
        (void)__hip_atomic_load(cnt, __ATOMIC_ACQUIRE, __HIP_MEMORY_SCOPE_AGENT);
    }
    __syncthreads();
}

// ---------------------------------------------------------------------------
// B-chunk staging, 2KB chunks (32 rows x 32 K). Global chunk id g in [0,64):
//   g<48: phase 1 -> t=g>>4, r=g&15, kc=r>>1, gf=r&1;
//         rows = Wgf[t][gf*256 + 32w .. +32)
//   g>=48: phase 2 -> c2=g-48, kc=c2>>1, half=c2&1;
//         rows = Wts[64w + 32*half .. +32)
// Per-wave slice [wave][buf<3][1024 hw]. Linear LDS dest (DMA rule);
// 16B-slot XOR pre-swizzle on the SOURCE, undone at read (bread).
// ---------------------------------------------------------------------------
__device__ __forceinline__ void stage32(
    const unsigned short* __restrict__ Wgf_k,
    const unsigned short* __restrict__ Wts_k,
    unsigned short* B_lds, int g, int buf, int w, int lane)
{
    const int rsub = lane >> 2;                       // 0..15 source row
    const int slot = (lane & 3) ^ ((lane >> 3) & 3);  // pre-swizzled src slot
    unsigned short* dst = B_lds + w * 3072 + buf * 1024;   // wave-uniform
    const unsigned short* src;
    if (g < 48) {
        const int t = g >> 4, r = g & 15, kc = r >> 1, gf = r & 1;
        src = Wgf_k + (t * 512 + gf * 256 + 32 * w) * 256 + kc * 32 + slot * 8;
    } else {
        const int c2 = g - 48, kc = c2 >> 1, half = c2 & 1;
        src = Wts_k + (64 * w + 32 * half) * 256 + kc * 32 + slot * 8;
    }
    gload_lds16(src + rsub * 256, dst);
    gload_lds16(src + (16 + rsub) * 256, dst + 512);
}

// read B fragment: local row r (0..31), k-quarter krow (0..3)
__device__ __forceinline__ bf16x8 bread(const unsigned short* Bw, int r, int krow)
{
    return *(const bf16x8*)(Bw + r * 32 + ((krow ^ ((r >> 1) & 3)) << 3));
}

// ---------------------------------------------------------------------------
__global__ __launch_bounds__(512, 2)
void wavenet_kernel(const float* __restrict__ x,
                    const float* __restrict__ init_w,
                    const float* __restrict__ init_b,
                    const unsigned short* __restrict__ Wib,
                    const float* __restrict__ ib,
                    const unsigned short* __restrict__ Wgf,
                    const unsigned short* __restrict__ Wts,
                    const float* __restrict__ gbA,
                    const float* __restrict__ fbA,
                    const unsigned short* __restrict__ Wfb,
                    const float* __restrict__ fbias,
                    unsigned short* __restrict__ Hb0,
                    unsigned short* __restrict__ Hb1,
                    float* __restrict__ out,
                    unsigned* __restrict__ counter)
{
    __shared__ __align__(16) unsigned short A_lds[3 * 64 * 256];   // 96 KB
    __shared__ __align__(16) unsigned short B_lds[8 * 3 * 1024];   // 48 KB

    const int tid  = threadIdx.x;
    const int lane = tid & 63;
    const int w    = tid >> 6;
    const int j0   = swz_jb(blockIdx.x) * 64;
    const int arow = lane & 15;
    const int krow = lane >> 4;
    const int aswz = (arow & 7) << 4;
    const int cg0  = w * 32;          // phase-1 gate/feat col base
    const int c0   = w * 64;          // H cols (w<4) base
    const int cs0  = (w - 4) * 64;    // S cols (w>=4) base

    // persistent fp32 masters: w<4 -> H cols [c0,c0+64); w>=4 -> S cols.
    f32x4 state[4][4];

    // ================= init conv -> state (waves 0-3), Hb0 + LDS tap1 ======
    if (w < 4) {
        #pragma unroll
        for (int ct = 0; ct < 4; ++ct) {
            const int col = c0 + ct * 16 + arow;
            const float w0 = init_w[col * 3];
            const float w1 = init_w[col * 3 + 1];
            const float w2 = init_w[col * 3 + 2];
            const float b  = init_b[col];
            #pragma unroll
            for (int mt = 0; mt < 4; ++mt)
                #pragma unroll
                for (int i = 0; i < 4; ++i) {
                    const int row = mt * 16 + krow * 4 + i;
                    const int j = j0 + row;
                    float acc = b + w1 * x[(j & 1) * 4096 + (j >> 1)];
                    int i2 = j - 2;
                    if (i2 >= 0) acc += w0 * x[(i2 & 1) * 4096 + (i2 >> 1)];
                    i2 = j + 2;
                    if (i2 < TS) acc += w2 * x[(i2 & 1) * 4096 + (i2 >> 1)];
                    state[mt][ct][i] = acc;
                    const unsigned short hb = f2bf(acc);
                    Hb0[(j << 8) + col] = hb;
                    A_lds[((64 + row) << 8) + (((col << 1) ^ ((row & 7) << 4)) >> 1)] = hb;
                }
        }
    }
    LGKM0(); SBAR();   // H0 (bf16) visible in tap1

    // ================= iskip -> state (waves 4-7) ==========================
    if (w >= 4) {
        #pragma unroll
        for (int ct = 0; ct < 4; ++ct) {
            const float b = ib[cs0 + ct * 16 + arow];
            #pragma unroll
            for (int mt = 0; mt < 4; ++mt)
                state[mt][ct] = (f32x4){b, b, b, b};
        }
        #pragma unroll
        for (int kc = 0; kc < 8; ++kc) {
            const int aoff = ((kc * 64 + krow * 16) ^ aswz) >> 1;
            bf16x8 a[4];
            #pragma unroll
            for (int mt = 0; mt < 4; ++mt)
                a[mt] = *(const bf16x8*)(A_lds + ((64 + mt * 16 + arow) << 8) + aoff);
            const int koff = kc * 32 + krow * 8;
            #pragma unroll
            for (int ct = 0; ct < 4; ++ct) {
                const bf16x8 bb = *(const bf16x8*)(Wib + ((cs0 + ct * 16 + arow) << 8) + koff);
                #pragma unroll
                for (int mt = 0; mt < 4; ++mt)
                    state[mt][ct] = MFMA16(a[mt], bb, state[mt][ct]);
            }
        }
    }

    // prefetch layer-0 chunks 0,1 (drained by the barrier's syncthreads)
    stage32(Wgf, Wts, B_lds, 0, 0, w, lane);
    stage32(Wgf, Wts, B_lds, 1, 1, w, lane);

    unsigned target = NBLK;
    grid_barrier(counter, target, tid);

    const unsigned short* Hb_in = Hb0;
    unsigned short*       Hb_out = Hb1;

    // ============================ layer loop ================================
    for (int k = 0; k < NL; ++k) {
        const int d = 2 << (k % 10);   // stream dilation = 2 * 2^(k%10)
        const unsigned short* Wgf_k = Wgf + (size_t)k * 393216;
        const unsigned short* Wts_k = Wts + (size_t)k * 131072;

        // ---- A-stage: taps 0 and 2 (center tap already in tap1 region) ----
        #pragma unroll
        for (int q = 0; q < 8; ++q) {
            const int cc  = tid + q * 512;      // 0..4095
            const int c16 = cc & 31;
            const int m   = (cc >> 5) & 63;
            const int tp  = (cc >> 11) << 1;    // 0 or 2
            const int r   = j0 + m + (tp - 1) * d;
            uint4 v = make_uint4(0u, 0u, 0u, 0u);
            if (r >= 0 && r < TS)
                v = *(const uint4*)(Hb_in + (r << 8) + (c16 << 3));
            const int sb = ((c16 << 4) ^ ((m & 7) << 4)) >> 1;
            *(uint4*)(A_lds + ((tp * 64 + m) << 8) + sb) = v;
        }
        LGKM0(); SBAR();   // A complete (chunks 0,1 DMA already landed)

        // ---- phase 1: 48 chunk-steps (tap x kc x gate/feat), ring-3 ----
        const float gv0 = gbA[k * 256 + cg0 + arow];
        const float gv1 = gbA[k * 256 + cg0 + 16 + arow];
        const float fv0 = fbA[k * 256 + cg0 + arow];
        const float fv1 = fbA[k * 256 + cg0 + 16 + arow];
        f32x4 accG[4][2], accF[4][2];
        #pragma unroll
        for (int mt = 0; mt < 4; ++mt) {
            accG[mt][0] = (f32x4){gv0, gv0, gv0, gv0};
            accG[mt][1] = (f32x4){gv1, gv1, gv1, gv1};
            accF[mt][0] = (f32x4){fv0, fv0, fv0, fv0};
            accF[mt][1] = (f32x4){fv1, fv1, fv1, fv1};
        }

        bf16x8 a[4];
        #pragma unroll
        for (int s = 0; s < 48; ++s) {
            stage32(Wgf_k, Wts_k, B_lds, s + 2, (s + 2) % 3, w, lane);
            VMW4();                                    // chunk s landed
            const int t = s >> 4, rr = s & 15, kc = rr >> 1, gf = rr & 1;
            if (gf == 0) {                             // A-frags shared by g/f pair
                const int aoff = ((kc * 64 + krow * 16) ^ aswz) >> 1;
                #pragma unroll
                for (int mt = 0; mt < 4; ++mt)
                    a[mt] = *(const bf16x8*)(A_lds + ((t * 64 + mt * 16 + arow) << 8) + aoff);
            }
            const unsigned short* Bw = B_lds + w * 3072 + (s % 3) * 1024;
            const bf16x8 b0 = bread(Bw, arow, krow);
            const bf16x8 b1 = bread(Bw, 16 + arow, krow);
            if (gf == 0) {
                #pragma unroll
                for (int mt = 0; mt < 4; ++mt) {
                    accG[mt][0] = MFMA16(a[mt], b0, accG[mt][0]);
                    accG[mt][1] = MFMA16(a[mt], b1, accG[mt][1]);
                }
            } else {
                #pragma unroll
                for (int mt = 0; mt < 4; ++mt) {
                    accF[mt][0] = MFMA16(a[mt], b0, accF[mt][0]);
                    accF[mt][1] = MFMA16(a[mt], b1, accF[mt][1]);
                }
            }
        }

        LGKM0(); SBAR();   // all conv tap reads done (tap0 reused for res)

        // ---- res = sigmoid(G)*tanh(F) -> tap0 (swizzled) ----
        #pragma unroll
        for (int mt = 0; mt < 4; ++mt)
            #pragma unroll
            for (int ct = 0; ct < 2; ++ct)
                #pragma unroll
                for (int i = 0; i < 4; ++i) {
                    const float g = accG[mt][ct][i];
                    const float f = accF[mt][ct][i];
                    const float sg = 1.0f / (1.0f + __expf(-g));
                    const float e2 = __expf(2.0f * f);
                    const float th = 1.0f - 2.0f / (e2 + 1.0f);
                    const float rr = sg * th;
                    const int row = mt * 16 + krow * 4 + i;
                    const int col = cg0 + ct * 16 + arow;
                    A_lds[(row << 8) + (((col << 1) ^ ((row & 7) << 4)) >> 1)] = f2bf(rr);
                }
        LGKM0(); SBAR();   // res visible (phase-2 chunks 0,1 in flight)

        // ---- phase 2: 16 chunk-steps; acc starts from persistent state ----
        f32x4 acc2[4][4];
        #pragma unroll
        for (int mt = 0; mt < 4; ++mt)
            #pragma unroll
            for (int ct = 0; ct < 4; ++ct)
                acc2[mt][ct] = state[mt][ct];

        #pragma unroll
        for (int p = 0; p < 16; ++p) {
            if (p <= 13)     { stage32(Wgf_k, Wts_k, B_lds, 50 + p, (50 + p) % 3, w, lane); VMW4(); }
            else if (p == 14){ VMW2(); }
            else             { VMW0(); }
            const int kc = p >> 1, half = p & 1;
            if (half == 0) {
                const int aoff = ((kc * 64 + krow * 16) ^ aswz) >> 1;
                #pragma unroll
                for (int mt = 0; mt < 4; ++mt)
                    a[mt] = *(const bf16x8*)(A_lds + ((mt * 16 + arow) << 8) + aoff);
            }
            const unsigned short* Bw = B_lds + w * 3072 + ((48 + p) % 3) * 1024;
            const bf16x8 b0 = bread(Bw, arow, krow);
            const bf16x8 b1 = bread(Bw, 16 + arow, krow);
            const int ct0 = half * 2;
            #pragma unroll
            for (int mt = 0; mt < 4; ++mt) {
                acc2[mt][ct0]     = MFMA16(a[mt], b0, acc2[mt][ct0]);
                acc2[mt][ct0 + 1] = MFMA16(a[mt], b1, acc2[mt][ct0 + 1]);
            }
        }

        // ---- state update (registers only) ----
        #pragma unroll
        for (int mt = 0; mt < 4; ++mt)
            #pragma unroll
            for (int ct = 0; ct < 4; ++ct)
                state[mt][ct] = acc2[mt][ct];

        if (k < NL - 1) {
            // prefetch next layer's chunks 0,1 (bufs 0,1 free after p=15)
            stage32(Wgf_k + 393216, Wts_k + 131072, B_lds, 0, 0, w, lane);
            stage32(Wgf_k + 393216, Wts_k + 131072, B_lds, 1, 1, w, lane);

            // waves 0-3: publish bf16 H to global (halo) + LDS tap1 (center)
            if (w < 4) {
                #pragma unroll
                for (int mt = 0; mt < 4; ++mt)
                    #pragma unroll
                    for (int ct = 0; ct < 4; ++ct)
                        #pragma unroll
                        for (int i = 0; i < 4; ++i) {
                            const int row = mt * 16 + krow * 4 + i;
                            const int col = c0 + ct * 16 + arow;
                            const unsigned short hb = f2bf(state[mt][ct][i]);
                            Hb_out[((j0 + row) << 8) + col] = hb;
                            A_lds[((64 + row) << 8) + (((col << 1) ^ ((row & 7) << 4)) >> 1)] = hb;
                        }
            }
            target += NBLK;
            grid_barrier(counter, target, tid);   // drains prefetch + publishes H

            unsigned short* tmp = (unsigned short*)Hb_in;
            Hb_in = Hb_out; Hb_out = tmp;
        } else {
            // last layer: S (waves 4-7) -> tap0 bf16 for the final GEMM
            LGKM0(); SBAR();   // all phase-2 tap0 reads done
            if (w >= 4) {
                #pragma unroll
                for (int mt = 0; mt < 4; ++mt)
                    #pragma unroll
                    for (int ct = 0; ct < 4; ++ct)
                        #pragma unroll
                        for (int i = 0; i < 4; ++i) {
                            const int row = mt * 16 + krow * 4 + i;
                            const int col = cs0 + ct * 16 + arow;
                            A_lds[(row << 8) + (((col << 1) ^ ((row & 7) << 4)) >> 1)] =
                                f2bf(state[mt][ct][i]);
                        }
            }
            LGKM0(); SBAR();
        }
    }

    // ================= final: out = Wfb @ S^T + fbias =======================
    {
        const int m0 = w * 32;   // co slice, 32 per wave
        f32x4 facc[2][4];
        #pragma unroll
        for (int cf = 0; cf < 2; ++cf)
            #pragma unroll
            for (int jf = 0; jf < 4; ++jf)
                facc[cf][jf] = (f32x4){0.f, 0.f, 0.f, 0.f};

        #pragma unroll
        for (int kc = 0; kc < 8; ++kc) {
            const int koff = kc * 32 + krow * 8;
            const bf16x8 a0 = *(const bf16x8*)(Wfb + ((m0 + arow) << 8) + koff);
            const bf16x8 a1 = *(const bf16x8*)(Wfb + ((m0 + 16 + arow) << 8) + koff);
            const int aoff = ((kc * 64 + krow * 16) ^ aswz) >> 1;
            #pragma unroll
            for (int jf = 0; jf < 4; ++jf) {
                const bf16x8 b = *(const bf16x8*)(A_lds + ((jf * 16 + arow) << 8) + aoff);
                facc[0][jf] = MFMA16(a0, b, facc[0][jf]);
                facc[1][jf] = MFMA16(a1, b, facc[1][jf]);
            }
        }

        #pragma unroll
        for (int cf = 0; cf < 2; ++cf)
            #pragma unroll
            for (int jf = 0; jf < 4; ++jf)
                #pragma unroll
                for (int i = 0; i < 4; ++i) {
                    const int co = m0 + cf * 16 + krow * 4 + i;
                    const int jj = j0 + jf * 16 + arow;
                    out[((jj & 1) << 20) + (co << 12) + (jj >> 1)] = facc[cf][jf][i] + fbias[co];
                }
    }
}

// ---------------------------------------------------------------------------
extern "C" void kernel_launch(void* const* d_in, const int* in_sizes, int n_in,
                              void* d_out, int out_size, void* d_ws, size_t ws_size,
                              hipStream_t stream)
{
    const float* x       = (const float*)d_in[0];
    const float* init_w  = (const float*)d_in[1];
    const float* init_b  = (const float*)d_in[2];
    const float* iskip_w = (const float*)d_in[3];
    const float* iskip_b = (const float*)d_in[4];
    const float* gate_w  = (const float*)d_in[5];
    const float* gate_b  = (const float*)d_in[6];
    const float* feat_w  = (const float*)d_in[7];
    const float* feat_b  = (const float*)d_in[8];
    const float* skip_w  = (const float*)d_in[9];
    const float* thru_w  = (const float*)d_in[10];
    const float* final_w = (const float*)d_in[11];
    const float* final_b = (const float*)d_in[12];

    char* ws = (char*)d_ws;
    size_t off = 0;
    auto alloc = [&](size_t bytes) {
        void* p = ws + off;
        off += (bytes + 255) & ~(size_t)255;
        return p;
    };
    unsigned short* Wgf = (unsigned short*)alloc((size_t)NL * 3 * 512 * 256 * 2);
    unsigned short* Wts = (unsigned short*)alloc((size_t)NL * 512 * 256 * 2);
    unsigned short* Wib = (unsigned short*)alloc(256 * 256 * 2);
    unsigned short* Wfb = (unsigned short*)alloc(256 * 256 * 2);
    unsigned short* Hb0 = (unsigned short*)alloc((size_t)TS * 256 * 2);
    unsigned short* Hb1 = (unsigned short*)alloc((size_t)TS * 256 * 2);
    unsigned*       cnt = (unsigned*)alloc(256);

    hipMemsetAsync((void*)cnt, 0, 256, stream);
    prep_weights_kernel<<<2048, 256, 0, stream>>>(gate_w, feat_w, thru_w, skip_w,
                                                  iskip_w, final_w, Wgf, Wts, Wib, Wfb);
    wavenet_kernel<<<NBLK, 512, 0, stream>>>(
        x, init_w, init_b, Wib, iskip_b, Wgf, Wts, gate_b, feat_b,
        Wfb, final_b, Hb0, Hb1, (float*)d_out, cnt);
}

// Round 12
// 926.185 us; speedup vs baseline: 1.7433x; 1.7433x over previous
//
#include <hip/hip_runtime.h>

// WaveNet (nsynth batch-folding) on MI355X — persistent kernel, v12.
// Stream identity: batch-folding dilation == dilated conv over one 8192-sample
// stream, j = l*2 + n; fold-d taps at j +- 2d, zero-pad at stream ends.
//
// v12 = v5 (proven 970us) with ONE change: weight-DMA pipeline depth 2 -> 4.
// Chunks shrink to 2KB (32 rows x 32 K, 2 global_load_lds each), ring-3 ->
// ring-6 in the same 96KB LDS footprint, vmcnt(8) now spans 4 chunks of
// prefetch instead of 2 (load latency ~600-900cy vs ~150cy step compute was
// the exposed stall). Accumulation order per accumulator is unchanged ->
// absmax must stay exactly 0.0625. Everything else is v5 verbatim: 256
// blocks x 8 waves, register H/S masters, tap1-from-epilogue, 1 grid
// barrier/layer, cross-barrier weight prefetch.

#define TS 8192
#define NL 30
#define NBLK 256

typedef __attribute__((ext_vector_type(8))) short bf16x8;
typedef __attribute__((ext_vector_type(4))) float f32x4;

__device__ __forceinline__ unsigned short f2bf(float f) {
    union { float f; unsigned int u; } v; v.f = f;
    unsigned int u = v.u;
    u += 0x7fffu + ((u >> 16) & 1u);   // RNE
    return (unsigned short)(u >> 16);
}

__device__ __forceinline__ void gload_lds16(const void* g, void* l) {
    __builtin_amdgcn_global_load_lds(
        (const __attribute__((address_space(1))) void*)g,
        (__attribute__((address_space(3))) void*)l, 16, 0, 0);
}

#define VMW8()  asm volatile("s_waitcnt vmcnt(8)" ::: "memory")
#define VMW6()  asm volatile("s_waitcnt vmcnt(6)" ::: "memory")
#define VMW4()  asm volatile("s_waitcnt vmcnt(4)" ::: "memory")
#define VMW2()  asm volatile("s_waitcnt vmcnt(2)" ::: "memory")
#define VMW0()  asm volatile("s_waitcnt vmcnt(0)" ::: "memory")
#define LGKM0() asm volatile("s_waitcnt lgkmcnt(0)" ::: "memory")
#define SBAR()  __builtin_amdgcn_s_barrier()
#define MFMA16(a, b, c) __builtin_amdgcn_mfma_f32_16x16x32_bf16((a), (b), (c), 0, 0, 0)

__device__ __forceinline__ int swz_jb(int bid) {   // XCD-chunked j-tile map
    return ((bid & 7) << 5) | (bid >> 3);
}

// ---------------------------------------------------------------------------
// Weight prep (v5 layout):
// Wgf[k][t][o][ci], o in [0,512): 0..255 gate, 256..511 feat (tap t split out)
// Wts[k][o][ci],    o in [0,512): 0..255 thru, 256..511 skip
// ---------------------------------------------------------------------------
__global__ void prep_weights_kernel(
    const float* __restrict__ gw, const float* __restrict__ fw,
    const float* __restrict__ tw, const float* __restrict__ sw,
    const float* __restrict__ iw, const float* __restrict__ fnw,
    unsigned short* __restrict__ Wgf, unsigned short* __restrict__ Wts,
    unsigned short* __restrict__ Wib, unsigned short* __restrict__ Wfb)
{
    const int idx = blockIdx.x * blockDim.x + threadIdx.x;
    const int stride = gridDim.x * blockDim.x;
    const int n_gf = NL * 3 * 512 * 256;
    for (int i = idx; i < n_gf; i += stride) {
        int ci = i & 255;
        int o  = (i >> 8) & 511;
        int r  = i >> 17;      // k*3 + t
        int t  = r % 3;
        int k  = r / 3;
        float v = (o < 256) ? gw[((k * 256 + o) * 256 + ci) * 3 + t]
                            : fw[((k * 256 + (o - 256)) * 256 + ci) * 3 + t];
        Wgf[i] = f2bf(v);
    }
    const int n_ts = NL * 512 * 256;
    for (int i = idx; i < n_ts; i += stride) {
        int ci = i & 255;
        int o  = (i >> 8) & 511;
        int k  = i >> 17;
        float v = (o < 256) ? tw[(k * 256 + o) * 256 + ci]
                            : sw[(k * 256 + (o - 256)) * 256 + ci];
        Wts[i] = f2bf(v);
    }
    for (int i = idx; i < 256 * 256; i += stride) Wib[i] = f2bf(iw[i]);
    for (int i = idx; i < 256 * 256; i += stride) Wfb[i] = f2bf(fnw[i]);
}

// ---------------------------------------------------------------------------
__device__ __forceinline__ void grid_barrier(unsigned* cnt, unsigned target, int tid) {
    __syncthreads();
    if (tid == 0) {
        __hip_atomic_fetch_add(cnt, 1u, __ATOMIC_RELEASE, __HIP_MEMORY_SCOPE_AGENT);
        while (__hip_atomic_load(cnt, __ATOMIC_RELAXED, __HIP_MEMORY_SCOPE_AGENT) < target)
            __builtin_amdgcn_s_sleep(2);
        (void)__hip_atomic_load(cnt, __ATOMIC_ACQUIRE, __HIP_MEMORY_SCOPE_AGENT);
    }
    __syncthreads();
}

// ---------------------------------------------------------------------------
// B-chunk staging, 2KB chunks (32 rows x 32 K), 8-wave geometry.
// Global chunk id g in [0,64):
//   g<48 : phase 1 -> t=g>>4, r=g&15, kc=r>>1, gf=r&1;
//          rows = Wgf[t][gf*256 + 32w .. +32)
//   g>=48: phase 2 -> c2=g-48, kc=c2>>1, half=c2&1;
//          rows = Wts[64w + 32*half .. +32)
// Per-wave slice [wave][buf<6][1024 hw]. Linear LDS dest (DMA rule);
// 16B-slot XOR pre-swizzle on the SOURCE, undone at read (bread).
// ---------------------------------------------------------------------------
__device__ __forceinline__ void stage32(
    const unsigned short* __restrict__ Wgf_k,
    const unsigned short* __restrict__ Wts_k,
    unsigned short* B_lds, int g, int w, int lane)
{
    const int buf  = g % 6;
    const int rsub = lane >> 2;                       // 0..15 source row
    const int slot = (lane & 3) ^ ((lane >> 3) & 3);  // pre-swizzled src slot
    unsigned short* dst = B_lds + w * 6144 + buf * 1024;   // wave-uniform
    const unsigned short* src;
    if (g < 48) {
        const int t = g >> 4, r = g & 15, kc = r >> 1, gf = r & 1;
        src = Wgf_k + (t * 512 + gf * 256 + 32 * w) * 256 + kc * 32 + slot * 8;
    } else {
        const int c2 = g - 48, kc = c2 >> 1, half = c2 & 1;
        src = Wts_k + (64 * w + 32 * half) * 256 + kc * 32 + slot * 8;
    }
    gload_lds16(src + rsub * 256, dst);
    gload_lds16(src + (16 + rsub) * 256, dst + 512);
}

// read B fragment: local row r (0..31), k-quarter krow (0..3)
__device__ __forceinline__ bf16x8 bread(const unsigned short* Bw, int r, int krow)
{
    return *(const bf16x8*)(Bw + r * 32 + ((krow ^ ((r >> 1) & 3)) << 3));
}

// ---------------------------------------------------------------------------
__global__ __launch_bounds__(512, 2)
void wavenet_kernel(const float* __restrict__ x,
                    const float* __restrict__ init_w,
                    const float* __restrict__ init_b,
                    const unsigned short* __restrict__ Wib,
                    const float* __restrict__ ib,
                    const unsigned short* __restrict__ Wgf,
                    const unsigned short* __restrict__ Wts,
                    const float* __restrict__ gbA,
                    const float* __restrict__ fbA,
                    const unsigned short* __restrict__ Wfb,
                    const float* __restrict__ fbias,
                    unsigned short* __restrict__ Hb0,
                    unsigned short* __restrict__ Hb1,
                    float* __restrict__ out,
                    unsigned* __restrict__ counter)
{
    __shared__ __align__(16) unsigned short A_lds[3 * 32 * 256];   // 48 KB
    __shared__ __align__(16) unsigned short B_lds[8 * 6 * 1024];   // 96 KB

    const int tid  = threadIdx.x;
    const int lane = tid & 63;
    const int w    = tid >> 6;
    const int j0   = swz_jb(blockIdx.x) * 32;
    const int arow = lane & 15;
    const int krow = lane >> 4;
    const int aswz = (arow & 7) << 4;
    const int cg0  = w * 32;
    const int c0   = w * 64;          // H cols (w<4) base
    const int cs0  = (w - 4) * 64;    // S cols (w>=4) base

    // persistent fp32 masters
    f32x4 state[2][4];

    // ================= init conv -> state (waves 0-3), Hb0 + LDS tap1 ======
    if (w < 4) {
        #pragma unroll
        for (int rt = 0; rt < 2; ++rt)
            #pragma unroll
            for (int fc = 0; fc < 4; ++fc) {
                #pragma unroll
                for (int i = 0; i < 4; ++i) {
                    const int row = rt * 16 + krow * 4 + i;
                    const int col = c0 + fc * 16 + arow;
                    const int j   = j0 + row;
                    float acc = init_b[col];
                    #pragma unroll
                    for (int t = 0; t < 3; ++t) {
                        const int i2 = j + 2 * t - 2;
                        if (i2 >= 0 && i2 < TS)
                            acc += init_w[col * 3 + t] * x[(i2 & 1) * 4096 + (i2 >> 1)];
                    }
                    state[rt][fc][i] = acc;
                    const unsigned short hb = f2bf(acc);
                    Hb0[(j << 8) + col] = hb;
                    A_lds[((32 + row) << 8) + (((col << 1) ^ ((row & 7) << 4)) >> 1)] = hb;
                }
            }
    }
    LGKM0(); SBAR();   // H0 (bf16) visible in tap1

    // ================= iskip -> state (waves 4-7) ==========================
    if (w >= 4) {
        #pragma unroll
        for (int rt = 0; rt < 2; ++rt)
            #pragma unroll
            for (int fc = 0; fc < 4; ++fc) {
                const float b = ib[cs0 + fc * 16 + arow];
                state[rt][fc] = (f32x4){b, b, b, b};
            }
        #pragma unroll
        for (int kc = 0; kc < 8; ++kc) {
            const int aoff = ((kc * 64 + krow * 16) ^ aswz) >> 1;
            const bf16x8 a0 = *(const bf16x8*)(A_lds + ((32 + arow) << 8) + aoff);
            const bf16x8 a1 = *(const bf16x8*)(A_lds + ((48 + arow) << 8) + aoff);
            const int koff = kc * 32 + krow * 8;
            #pragma unroll
            for (int fc = 0; fc < 4; ++fc) {
                const bf16x8 bb = *(const bf16x8*)(Wib + ((cs0 + fc * 16 + arow) << 8) + koff);
                state[0][fc] = MFMA16(a0, bb, state[0][fc]);
                state[1][fc] = MFMA16(a1, bb, state[1][fc]);
            }
        }
    }

    // pre-stage layer-0 chunks 0..3 (drained by the grid barrier)
    stage32(Wgf, Wts, B_lds, 0, w, lane);
    stage32(Wgf, Wts, B_lds, 1, w, lane);
    stage32(Wgf, Wts, B_lds, 2, w, lane);
    stage32(Wgf, Wts, B_lds, 3, w, lane);

    unsigned target = NBLK;
    grid_barrier(counter, target, tid);

    const unsigned short* Hb_in = Hb0;
    unsigned short*       Hb_out = Hb1;

    // ============================ layer loop ================================
    for (int k = 0; k < NL; ++k) {
        const int d = 2 << (k % 10);   // stream dilation = 2 * 2^(k%10)
        const unsigned short* Wgf_k = Wgf + (size_t)k * 393216;
        const unsigned short* Wts_k = Wts + (size_t)k * 131072;

        // ---- A-stage: taps 0 and 2 only (center tap already in tap1) ----
        #pragma unroll
        for (int q = 0; q < 4; ++q) {
            const int cc  = tid + q * 512;
            const int c16 = cc & 31;
            const int m   = (cc >> 5) & 31;
            const int t   = (cc >> 10) << 1;            // 0 or 2
            const int r   = j0 + m + (t - 1) * d;
            uint4 v = make_uint4(0u, 0u, 0u, 0u);
            if (r >= 0 && r < TS)
                v = *(const uint4*)(Hb_in + (r << 8) + (c16 << 3));
            const int sb = (c16 << 4) ^ ((m & 7) << 4);
            *(uint4*)(A_lds + ((t * 32 + m) << 8) + (sb >> 1)) = v;
        }
        LGKM0(); SBAR();   // A complete (chunks 0..3 DMA already landed)

        // ---- phase 1: 48 chunk-steps (t x kc x gate/feat), ring-6 ----
        const float gv0 = gbA[k * 256 + cg0 + arow];
        const float gv1 = gbA[k * 256 + cg0 + 16 + arow];
        const float fv0 = fbA[k * 256 + cg0 + arow];
        const float fv1 = fbA[k * 256 + cg0 + 16 + arow];
        f32x4 accG[2][2], accF[2][2];
        accG[0][0] = (f32x4){gv0, gv0, gv0, gv0}; accG[1][0] = accG[0][0];
        accG[0][1] = (f32x4){gv1, gv1, gv1, gv1}; accG[1][1] = accG[0][1];
        accF[0][0] = (f32x4){fv0, fv0, fv0, fv0}; accF[1][0] = accF[0][0];
        accF[0][1] = (f32x4){fv1, fv1, fv1, fv1}; accF[1][1] = accF[0][1];

        bf16x8 a0, a1;
        #pragma unroll
        for (int s = 0; s < 48; ++s) {
            stage32(Wgf_k, Wts_k, B_lds, s + 4, w, lane);   // s+4 <= 51
            VMW8();                                         // chunk s landed
            const int t = s >> 4, rr = s & 15, kc = rr >> 1, gf = rr & 1;
            if (gf == 0) {                                  // A shared by g/f pair
                const int aoff = ((kc * 64 + krow * 16) ^ aswz) >> 1;
                const unsigned short* At = A_lds + ((t * 32 + arow) << 8);
                a0 = *(const bf16x8*)(At + aoff);
                a1 = *(const bf16x8*)(At + (16 << 8) + aoff);
            }
            const unsigned short* Bw = B_lds + w * 6144 + (s % 6) * 1024;
            const bf16x8 b0 = bread(Bw, arow, krow);
            const bf16x8 b1 = bread(Bw, 16 + arow, krow);
            if (gf == 0) {
                accG[0][0] = MFMA16(a0, b0, accG[0][0]);
                accG[1][0] = MFMA16(a1, b0, accG[1][0]);
                accG[0][1] = MFMA16(a0, b1, accG[0][1]);
                accG[1][1] = MFMA16(a1, b1, accG[1][1]);
            } else {
                accF[0][0] = MFMA16(a0, b0, accF[0][0]);
                accF[1][0] = MFMA16(a1, b0, accF[1][0]);
                accF[0][1] = MFMA16(a0, b1, accF[0][1]);
                accF[1][1] = MFMA16(a1, b1, accF[1][1]);
            }
        }

        LGKM0(); SBAR();   // phase-1 LDS reads done (tap0 reused for res)

        // ---- res = sigmoid(G)*tanh(F) -> tap0 (swizzled) ----
        #pragma unroll
        for (int rt = 0; rt < 2; ++rt)
            #pragma unroll
            for (int fc = 0; fc < 2; ++fc)
                #pragma unroll
                for (int i = 0; i < 4; ++i) {
                    const float g = accG[rt][fc][i];
                    const float f = accF[rt][fc][i];
                    const float sg = 1.0f / (1.0f + __expf(-g));
                    const float e2 = __expf(2.0f * f);
                    const float th = 1.0f - 2.0f / (e2 + 1.0f);
                    const float rr = sg * th;
                    const int row = rt * 16 + krow * 4 + i;
                    const int col = cg0 + fc * 16 + arow;
                    A_lds[(row << 8) + (((col << 1) ^ ((row & 7) << 4)) >> 1)] = f2bf(rr);
                }
        LGKM0(); SBAR();   // res visible (chunks 48..51 in flight)

        // ---- phase 2: 16 chunk-steps; acc starts from persistent state ----
        f32x4 acc2[2][4];
        #pragma unroll
        for (int rt = 0; rt < 2; ++rt)
            #pragma unroll
            for (int fc = 0; fc < 4; ++fc)
                acc2[rt][fc] = state[rt][fc];

        #pragma unroll
        for (int p = 0; p < 16; ++p) {
            if (p <= 11)      { stage32(Wgf_k, Wts_k, B_lds, 52 + p, w, lane); VMW8(); }
            else if (p == 12) { VMW6(); }
            else if (p == 13) { VMW4(); }
            else if (p == 14) { VMW2(); }
            else              { VMW0(); }
            const int kc = p >> 1, half = p & 1;
            if (half == 0) {
                const int aoff = ((kc * 64 + krow * 16) ^ aswz) >> 1;
                a0 = *(const bf16x8*)(A_lds + (arow << 8) + aoff);
                a1 = *(const bf16x8*)(A_lds + ((16 + arow) << 8) + aoff);
            }
            const unsigned short* Bw = B_lds + w * 6144 + ((48 + p) % 6) * 1024;
            const bf16x8 b0 = bread(Bw, arow, krow);
            const bf16x8 b1 = bread(Bw, 16 + arow, krow);
            const int ct0 = half * 2;
            acc2[0][ct0]     = MFMA16(a0, b0, acc2[0][ct0]);
            acc2[1][ct0]     = MFMA16(a1, b0, acc2[1][ct0]);
            acc2[0][ct0 + 1] = MFMA16(a0, b1, acc2[0][ct0 + 1]);
            acc2[1][ct0 + 1] = MFMA16(a1, b1, acc2[1][ct0 + 1]);
        }

        // ---- state update (registers only) ----
        #pragma unroll
        for (int rt = 0; rt < 2; ++rt)
            #pragma unroll
            for (int fc = 0; fc < 4; ++fc)
                state[rt][fc] = acc2[rt][fc];

        if (k < NL - 1) {
            // prefetch next layer's chunks 0..3 (slots 0..3 free after p=15)
            stage32(Wgf_k + 393216, Wts_k + 131072, B_lds, 0, w, lane);
            stage32(Wgf_k + 393216, Wts_k + 131072, B_lds, 1, w, lane);
            stage32(Wgf_k + 393216, Wts_k + 131072, B_lds, 2, w, lane);
            stage32(Wgf_k + 393216, Wts_k + 131072, B_lds, 3, w, lane);

            // waves 0-3: publish bf16 H to global (halo) + LDS tap1 (center)
            if (w < 4) {
                #pragma unroll
                for (int rt = 0; rt < 2; ++rt)
                    #pragma unroll
                    for (int fc = 0; fc < 4; ++fc)
                        #pragma unroll
                        for (int i = 0; i < 4; ++i) {
                            const int row = rt * 16 + krow * 4 + i;
                            const int col = c0 + fc * 16 + arow;
                            const unsigned short hb = f2bf(state[rt][fc][i]);
                            Hb_out[((j0 + row) << 8) + col] = hb;
                            A_lds[((32 + row) << 8) + (((col << 1) ^ ((row & 7) << 4)) >> 1)] = hb;
                        }
            }
            target += NBLK;
            grid_barrier(counter, target, tid);   // drains prefetch + publishes H

            unsigned short* tmp = (unsigned short*)Hb_in;
            Hb_in = Hb_out; Hb_out = tmp;
        } else {
            // last layer: S (waves 4-7) -> tap0 bf16 for the final GEMM
            LGKM0(); SBAR();   // all phase-2 tap0 reads done
            if (w >= 4) {
                #pragma unroll
                for (int rt = 0; rt < 2; ++rt)
                    #pragma unroll
                    for (int fc = 0; fc < 4; ++fc)
                        #pragma unroll
                        for (int i = 0; i < 4; ++i) {
                            const int row = rt * 16 + krow * 4 + i;
                            const int col = cs0 + fc * 16 + arow;
                            A_lds[(row << 8) + (((col << 1) ^ ((row & 7) << 4)) >> 1)] =
                                f2bf(state[rt][fc][i]);
                        }
            }
            LGKM0(); SBAR();
        }
    }

    // ================= final: out = Wfb @ S^T + fbias =======================
    {
        const int m0 = w * 32;   // co slice
        f32x4 facc[2][2];
        #pragma unroll
        for (int rt = 0; rt < 2; ++rt)
            #pragma unroll
            for (int fc = 0; fc < 2; ++fc)
                facc[rt][fc] = (f32x4){0.f, 0.f, 0.f, 0.f};

        #pragma unroll
        for (int kc = 0; kc < 8; ++kc) {
            const int koff = kc * 32 + krow * 8;
            const bf16x8 a0 = *(const bf16x8*)(Wfb + ((m0 + arow) << 8) + koff);
            const bf16x8 a1 = *(const bf16x8*)(Wfb + ((m0 + 16 + arow) << 8) + koff);
            const int aoff = ((kc * 64 + krow * 16) ^ aswz) >> 1;
            const bf16x8 b0 = *(const bf16x8*)(A_lds + (arow << 8) + aoff);
            const bf16x8 b1 = *(const bf16x8*)(A_lds + ((16 + arow) << 8) + aoff);
            facc[0][0] = MFMA16(a0, b0, facc[0][0]);
            facc[1][0] = MFMA16(a1, b0, facc[1][0]);
            facc[0][1] = MFMA16(a0, b1, facc[0][1]);
            facc[1][1] = MFMA16(a1, b1, facc[1][1]);
        }

        #pragma unroll
        for (int rt = 0; rt < 2; ++rt)
            #pragma unroll
            for (int fc = 0; fc < 2; ++fc)
                #pragma unroll
                for (int i = 0; i < 4; ++i) {
                    const int co = m0 + rt * 16 + krow * 4 + i;
                    const int jj = j0 + fc * 16 + arow;
                    out[((jj & 1) << 20) + (co << 12) + (jj >> 1)] = facc[rt][fc][i] + fbias[co];
                }
    }
}

// ---------------------------------------------------------------------------
extern "C" void kernel_launch(void* const* d_in, const int* in_sizes, int n_in,
                              void* d_out, int out_size, void* d_ws, size_t ws_size,
                              hipStream_t stream)
{
    const float* x       = (const float*)d_in[0];
    const float* init_w  = (const float*)d_in[1];
    const float* init_b  = (const float*)d_in[2];
    const float* iskip_w = (const float*)d_in[3];
    const float* iskip_b = (const float*)d_in[4];
    const float* gate_w  = (const float*)d_in[5];
    const float* gate_b  = (const float*)d_in[6];
    const float* feat_w  = (const float*)d_in[7];
    const float* feat_b  = (const float*)d_in[8];
    const float* skip_w  = (const float*)d_in[9];
    const float* thru_w  = (const float*)d_in[10];
    const float* final_w = (const float*)d_in[11];
    const float* final_b = (const float*)d_in[12];

    char* ws = (char*)d_ws;
    size_t off = 0;
    auto alloc = [&](size_t bytes) {
        void* p = ws + off;
        off += (bytes + 255) & ~(size_t)255;
        return p;
    };
    unsigned short* Wgf = (unsigned short*)alloc((size_t)NL * 3 * 512 * 256 * 2);
    unsigned short* Wts = (unsigned short*)alloc((size_t)NL * 512 * 256 * 2);
    unsigned short* Wib = (unsigned short*)alloc(256 * 256 * 2);
    unsigned short* Wfb = (unsigned short*)alloc(256 * 256 * 2);
    unsigned short* Hb0 = (unsigned short*)alloc((size_t)TS * 256 * 2);
    unsigned short* Hb1 = (unsigned short*)alloc((size_t)TS * 256 * 2);
    unsigned*       cnt = (unsigned*)alloc(256);

    hipMemsetAsync((void*)cnt, 0, 256, stream);
    prep_weights_kernel<<<2048, 256, 0, stream>>>(gate_w, feat_w, thru_w, skip_w,
                                                  iskip_w, final_w, Wgf, Wts, Wib, Wfb);
    wavenet_kernel<<<NBLK, 512, 0, stream>>>(
        x, init_w, init_b, Wib, iskip_b, Wgf, Wts, gate_b, feat_b,
        Wfb, final_b, Hb0, Hb1, (float*)d_out, cnt);
}

// Round 13
// 749.170 us; speedup vs baseline: 2.1552x; 1.2363x over previous
//
#include <hip/hip_runtime.h>

// WaveNet (nsynth batch-folding) on MI355X — persistent kernel, v13.
// Stream identity: batch-folding dilation == dilated conv over one 8192-sample
// stream, j = l*2 + n; fold-d taps at j +- 2d, zero-pad at stream ends.
//
// v13 = v12 with ONE change: weights pre-packed into DMA-BURST order (WF).
// v12's global_load_lds bursts read 16 lines at 512B stride (rows) -> L2 bank
// clustering (~4x read inefficiency, the measured 32us vs ~8us L2 floor).
// WF stores each (layer, chunk g<64, wave, inst<2) 1KB block contiguously,
// lane i owning bytes [16i,16i+16) = exactly the element v12's DMA slot
// carried. stage32 reads two sequential 1KB bursts -> 16 consecutive lines
// per instruction. LDS image is bit-identical to v12 (bread/MFMA/numerics
// untouched -> absmax exactly 0.0625). Everything else is v12 verbatim:
// 256 blocks x 8 waves, 2KB chunks ring-6 vmcnt(8) depth-4, register H/S
// masters, tap1-from-epilogue, 1 grid barrier/layer, cross-barrier prefetch.

#define TS 8192
#define NL 30
#define NBLK 256
#define WF_LAYER 524288   // halfwords per layer = 64 chunks x 8 waves x 1024

typedef __attribute__((ext_vector_type(8))) short bf16x8;
typedef __attribute__((ext_vector_type(4))) float f32x4;

__device__ __forceinline__ unsigned short f2bf(float f) {
    union { float f; unsigned int u; } v; v.f = f;
    unsigned int u = v.u;
    u += 0x7fffu + ((u >> 16) & 1u);   // RNE
    return (unsigned short)(u >> 16);
}

__device__ __forceinline__ void gload_lds16(const void* g, void* l) {
    __builtin_amdgcn_global_load_lds(
        (const __attribute__((address_space(1))) void*)g,
        (__attribute__((address_space(3))) void*)l, 16, 0, 0);
}

#define VMW8()  asm volatile("s_waitcnt vmcnt(8)" ::: "memory")
#define VMW6()  asm volatile("s_waitcnt vmcnt(6)" ::: "memory")
#define VMW4()  asm volatile("s_waitcnt vmcnt(4)" ::: "memory")
#define VMW2()  asm volatile("s_waitcnt vmcnt(2)" ::: "memory")
#define VMW0()  asm volatile("s_waitcnt vmcnt(0)" ::: "memory")
#define LGKM0() asm volatile("s_waitcnt lgkmcnt(0)" ::: "memory")
#define SBAR()  __builtin_amdgcn_s_barrier()
#define MFMA16(a, b, c) __builtin_amdgcn_mfma_f32_16x16x32_bf16((a), (b), (c), 0, 0, 0)

__device__ __forceinline__ int swz_jb(int bid) {   // XCD-chunked j-tile map
    return ((bid & 7) << 5) | (bid >> 3);
}

// ---------------------------------------------------------------------------
// Weight prep -> WF fragment-burst layout.
// WF halfword offset: ((k*64 + g)*8 + w)*1024 + inst*512 + lane*8 + e
// Element carried (matches v12 stage32's lane->(rsub,slot) DMA mapping):
//   rsub = lane>>2, slot = (lane&3)^((lane>>3)&3), col = kc*32 + slot*8 + e
//   g<48 : t=g>>4, r=g&15, kc=r>>1, gf=r&1;
//          o = gf*256 + 32w + inst*16 + rsub  (tap-t gate/feat row)
//   g>=48: c2=g-48, kc=c2>>1, half=c2&1;
//          o = 64w + 32*half + inst*16 + rsub (thru||skip row)
// Wib/Wfb unchanged (small, one-shot users).
// ---------------------------------------------------------------------------
__global__ void prep_weights_kernel(
    const float* __restrict__ gw, const float* __restrict__ fw,
    const float* __restrict__ tw, const float* __restrict__ sw,
    const float* __restrict__ iw, const float* __restrict__ fnw,
    unsigned short* __restrict__ WF,
    unsigned short* __restrict__ Wib, unsigned short* __restrict__ Wfb)
{
    const int idx = blockIdx.x * blockDim.x + threadIdx.x;
    const int stride = gridDim.x * blockDim.x;
    const int total = NL * 64 * 8 * 2 * 64;   // (k,g,w,inst,lane) groups of 8
    for (int i = idx; i < total; i += stride) {
        const int lane = i & 63;
        const int inst = (i >> 6) & 1;
        const int w    = (i >> 7) & 7;
        const int g    = (i >> 10) & 63;
        const int k    = i >> 16;
        const int rsub = lane >> 2;
        const int slot = (lane & 3) ^ ((lane >> 3) & 3);
        unsigned short* dst = WF + (size_t)((k * 64 + g) * 8 + w) * 1024
                                 + inst * 512 + lane * 8;
        if (g < 48) {
            const int t = g >> 4, r = g & 15, kc = r >> 1, gf = r & 1;
            const int o   = gf * 256 + 32 * w + inst * 16 + rsub;
            const int col = kc * 32 + slot * 8;
            if (o < 256) {
                const float* src = gw + ((size_t)(k * 256 + o) * 256 + col) * 3 + t;
                #pragma unroll
                for (int e = 0; e < 8; ++e) dst[e] = f2bf(src[e * 3]);
            } else {
                const float* src = fw + ((size_t)(k * 256 + (o - 256)) * 256 + col) * 3 + t;
                #pragma unroll
                for (int e = 0; e < 8; ++e) dst[e] = f2bf(src[e * 3]);
            }
        } else {
            const int c2 = g - 48, kc = c2 >> 1, half = c2 & 1;
            const int o   = 64 * w + 32 * half + inst * 16 + rsub;
            const int col = kc * 32 + slot * 8;
            if (o < 256) {
                const float* src = tw + (size_t)(k * 256 + o) * 256 + col;
                #pragma unroll
                for (int e = 0; e < 8; ++e) dst[e] = f2bf(src[e]);
            } else {
                const float* src = sw + (size_t)(k * 256 + (o - 256)) * 256 + col;
                #pragma unroll
                for (int e = 0; e < 8; ++e) dst[e] = f2bf(src[e]);
            }
        }
    }
    for (int i = idx; i < 256 * 256; i += stride) Wib[i] = f2bf(iw[i]);
    for (int i = idx; i < 256 * 256; i += stride) Wfb[i] = f2bf(fnw[i]);
}

// ---------------------------------------------------------------------------
__device__ __forceinline__ void grid_barrier(unsigned* cnt, unsigned target, int tid) {
    __syncthreads();
    if (tid == 0) {
        __hip_atomic_fetch_add(cnt, 1u, __ATOMIC_RELEASE, __HIP_MEMORY_SCOPE_AGENT);
        while (__hip_atomic_load(cnt, __ATOMIC_RELAXED, __HIP_MEMORY_SCOPE_AGENT) < target)
            __builtin_amdgcn_s_sleep(2);
        (void)__hip_atomic_load(cnt, __ATOMIC_ACQUIRE, __HIP_MEMORY_SCOPE_AGENT);
    }
    __syncthreads();
}

// ---------------------------------------------------------------------------
// B-chunk staging from WF: chunk g in [0,64), per-wave 2KB contiguous block,
// two fully-coalesced 1KB bursts (lane i -> bytes [16i,16i+16)). LDS dest
// uniform (DMA rule); resulting LDS image == v12's. Ring-6 per wave.
// ---------------------------------------------------------------------------
__device__ __forceinline__ void stage32(
    const unsigned short* __restrict__ WFk,
    unsigned short* B_lds, int g, int w, int lane)
{
    const int buf = g % 6;
    unsigned short* dst = B_lds + w * 6144 + buf * 1024;
    const unsigned short* src = WFk + ((g * 8 + w) << 10) + lane * 8;
    gload_lds16(src, dst);
    gload_lds16(src + 512, dst + 512);
}

// read B fragment: local row r (0..31), k-quarter krow (0..3)
__device__ __forceinline__ bf16x8 bread(const unsigned short* Bw, int r, int krow)
{
    return *(const bf16x8*)(Bw + r * 32 + ((krow ^ ((r >> 1) & 3)) << 3));
}

// ---------------------------------------------------------------------------
__global__ __launch_bounds__(512, 2)
void wavenet_kernel(const float* __restrict__ x,
                    const float* __restrict__ init_w,
                    const float* __restrict__ init_b,
                    const unsigned short* __restrict__ Wib,
                    const float* __restrict__ ib,
                    const unsigned short* __restrict__ WF,
                    const float* __restrict__ gbA,
                    const float* __restrict__ fbA,
                    const unsigned short* __restrict__ Wfb,
                    const float* __restrict__ fbias,
                    unsigned short* __restrict__ Hb0,
                    unsigned short* __restrict__ Hb1,
                    float* __restrict__ out,
                    unsigned* __restrict__ counter)
{
    __shared__ __align__(16) unsigned short A_lds[3 * 32 * 256];   // 48 KB
    __shared__ __align__(16) unsigned short B_lds[8 * 6 * 1024];   // 96 KB

    const int tid  = threadIdx.x;
    const int lane = tid & 63;
    const int w    = tid >> 6;
    const int j0   = swz_jb(blockIdx.x) * 32;
    const int arow = lane & 15;
    const int krow = lane >> 4;
    const int aswz = (arow & 7) << 4;
    const int cg0  = w * 32;
    const int c0   = w * 64;          // H cols (w<4) base
    const int cs0  = (w - 4) * 64;    // S cols (w>=4) base

    // persistent fp32 masters
    f32x4 state[2][4];

    // ================= init conv -> state (waves 0-3), Hb0 + LDS tap1 ======
    if (w < 4) {
        #pragma unroll
        for (int rt = 0; rt < 2; ++rt)
            #pragma unroll
            for (int fc = 0; fc < 4; ++fc) {
                #pragma unroll
                for (int i = 0; i < 4; ++i) {
                    const int row = rt * 16 + krow * 4 + i;
                    const int col = c0 + fc * 16 + arow;
                    const int j   = j0 + row;
                    float acc = init_b[col];
                    #pragma unroll
                    for (int t = 0; t < 3; ++t) {
                        const int i2 = j + 2 * t - 2;
                        if (i2 >= 0 && i2 < TS)
                            acc += init_w[col * 3 + t] * x[(i2 & 1) * 4096 + (i2 >> 1)];
                    }
                    state[rt][fc][i] = acc;
                    const unsigned short hb = f2bf(acc);
                    Hb0[(j << 8) + col] = hb;
                    A_lds[((32 + row) << 8) + (((col << 1) ^ ((row & 7) << 4)) >> 1)] = hb;
                }
            }
    }
    LGKM0(); SBAR();   // H0 (bf16) visible in tap1

    // ================= iskip -> state (waves 4-7) ==========================
    if (w >= 4) {
        #pragma unroll
        for (int rt = 0; rt < 2; ++rt)
            #pragma unroll
            for (int fc = 0; fc < 4; ++fc) {
                const float b = ib[cs0 + fc * 16 + arow];
                state[rt][fc] = (f32x4){b, b, b, b};
            }
        #pragma unroll
        for (int kc = 0; kc < 8; ++kc) {
            const int aoff = ((kc * 64 + krow * 16) ^ aswz) >> 1;
            const bf16x8 a0 = *(const bf16x8*)(A_lds + ((32 + arow) << 8) + aoff);
            const bf16x8 a1 = *(const bf16x8*)(A_lds + ((48 + arow) << 8) + aoff);
            const int koff = kc * 32 + krow * 8;
            #pragma unroll
            for (int fc = 0; fc < 4; ++fc) {
                const bf16x8 bb = *(const bf16x8*)(Wib + ((cs0 + fc * 16 + arow) << 8) + koff);
                state[0][fc] = MFMA16(a0, bb, state[0][fc]);
                state[1][fc] = MFMA16(a1, bb, state[1][fc]);
            }
        }
    }

    // pre-stage layer-0 chunks 0..3 (drained by the grid barrier)
    stage32(WF, B_lds, 0, w, lane);
    stage32(WF, B_lds, 1, w, lane);
    stage32(WF, B_lds, 2, w, lane);
    stage32(WF, B_lds, 3, w, lane);

    unsigned target = NBLK;
    grid_barrier(counter, target, tid);

    const unsigned short* Hb_in = Hb0;
    unsigned short*       Hb_out = Hb1;

    // ============================ layer loop ================================
    for (int k = 0; k < NL; ++k) {
        const int d = 2 << (k % 10);   // stream dilation = 2 * 2^(k%10)
        const unsigned short* WFk = WF + (size_t)k * WF_LAYER;

        // ---- A-stage: taps 0 and 2 only (center tap already in tap1) ----
        #pragma unroll
        for (int q = 0; q < 4; ++q) {
            const int cc  = tid + q * 512;
            const int c16 = cc & 31;
            const int m   = (cc >> 5) & 31;
            const int t   = (cc >> 10) << 1;            // 0 or 2
            const int r   = j0 + m + (t - 1) * d;
            uint4 v = make_uint4(0u, 0u, 0u, 0u);
            if (r >= 0 && r < TS)
                v = *(const uint4*)(Hb_in + (r << 8) + (c16 << 3));
            const int sb = (c16 << 4) ^ ((m & 7) << 4);
            *(uint4*)(A_lds + ((t * 32 + m) << 8) + (sb >> 1)) = v;
        }
        LGKM0(); SBAR();   // A complete (chunks 0..3 DMA already landed)

        // ---- phase 1: 48 chunk-steps (t x kc x gate/feat), ring-6 ----
        const float gv0 = gbA[k * 256 + cg0 + arow];
        const float gv1 = gbA[k * 256 + cg0 + 16 + arow];
        const float fv0 = fbA[k * 256 + cg0 + arow];
        const float fv1 = fbA[k * 256 + cg0 + 16 + arow];
        f32x4 accG[2][2], accF[2][2];
        accG[0][0] = (f32x4){gv0, gv0, gv0, gv0}; accG[1][0] = accG[0][0];
        accG[0][1] = (f32x4){gv1, gv1, gv1, gv1}; accG[1][1] = accG[0][1];
        accF[0][0] = (f32x4){fv0, fv0, fv0, fv0}; accF[1][0] = accF[0][0];
        accF[0][1] = (f32x4){fv1, fv1, fv1, fv1}; accF[1][1] = accF[0][1];

        bf16x8 a0, a1;
        #pragma unroll
        for (int s = 0; s < 48; ++s) {
            stage32(WFk, B_lds, s + 4, w, lane);   // s+4 <= 51
            VMW8();                                // chunk s landed
            const int t = s >> 4, rr = s & 15, kc = rr >> 1, gf = rr & 1;
            if (gf == 0) {                         // A shared by g/f pair
                const int aoff = ((kc * 64 + krow * 16) ^ aswz) >> 1;
                const unsigned short* At = A_lds + ((t * 32 + arow) << 8);
                a0 = *(const bf16x8*)(At + aoff);
                a1 = *(const bf16x8*)(At + (16 << 8) + aoff);
            }
            const unsigned short* Bw = B_lds + w * 6144 + (s % 6) * 1024;
            const bf16x8 b0 = bread(Bw, arow, krow);
            const bf16x8 b1 = bread(Bw, 16 + arow, krow);
            if (gf == 0) {
                accG[0][0] = MFMA16(a0, b0, accG[0][0]);
                accG[1][0] = MFMA16(a1, b0, accG[1][0]);
                accG[0][1] = MFMA16(a0, b1, accG[0][1]);
                accG[1][1] = MFMA16(a1, b1, accG[1][1]);
            } else {
                accF[0][0] = MFMA16(a0, b0, accF[0][0]);
                accF[1][0] = MFMA16(a1, b0, accF[1][0]);
                accF[0][1] = MFMA16(a0, b1, accF[0][1]);
                accF[1][1] = MFMA16(a1, b1, accF[1][1]);
            }
        }

        LGKM0(); SBAR();   // phase-1 LDS reads done (tap0 reused for res)

        // ---- res = sigmoid(G)*tanh(F) -> tap0 (swizzled) ----
        #pragma unroll
        for (int rt = 0; rt < 2; ++rt)
            #pragma unroll
            for (int fc = 0; fc < 2; ++fc)
                #pragma unroll
                for (int i = 0; i < 4; ++i) {
                    const float g = accG[rt][fc][i];
                    const float f = accF[rt][fc][i];
                    const float sg = 1.0f / (1.0f + __expf(-g));
                    const float e2 = __expf(2.0f * f);
                    const float th = 1.0f - 2.0f / (e2 + 1.0f);
                    const float rr = sg * th;
                    const int row = rt * 16 + krow * 4 + i;
                    const int col = cg0 + fc * 16 + arow;
                    A_lds[(row << 8) + (((col << 1) ^ ((row & 7) << 4)) >> 1)] = f2bf(rr);
                }
        LGKM0(); SBAR();   // res visible (chunks 48..51 in flight)

        // ---- phase 2: 16 chunk-steps; acc starts from persistent state ----
        f32x4 acc2[2][4];
        #pragma unroll
        for (int rt = 0; rt < 2; ++rt)
            #pragma unroll
            for (int fc = 0; fc < 4; ++fc)
                acc2[rt][fc] = state[rt][fc];

        #pragma unroll
        for (int p = 0; p < 16; ++p) {
            if (p <= 11)      { stage32(WFk, B_lds, 52 + p, w, lane); VMW8(); }
            else if (p == 12) { VMW6(); }
            else if (p == 13) { VMW4(); }
            else if (p == 14) { VMW2(); }
            else              { VMW0(); }
            const int kc = p >> 1, half = p & 1;
            if (half == 0) {
                const int aoff = ((kc * 64 + krow * 16) ^ aswz) >> 1;
                a0 = *(const bf16x8*)(A_lds + (arow << 8) + aoff);
                a1 = *(const bf16x8*)(A_lds + ((16 + arow) << 8) + aoff);
            }
            const unsigned short* Bw = B_lds + w * 6144 + ((48 + p) % 6) * 1024;
            const bf16x8 b0 = bread(Bw, arow, krow);
            const bf16x8 b1 = bread(Bw, 16 + arow, krow);
            const int ct0 = half * 2;
            acc2[0][ct0]     = MFMA16(a0, b0, acc2[0][ct0]);
            acc2[1][ct0]     = MFMA16(a1, b0, acc2[1][ct0]);
            acc2[0][ct0 + 1] = MFMA16(a0, b1, acc2[0][ct0 + 1]);
            acc2[1][ct0 + 1] = MFMA16(a1, b1, acc2[1][ct0 + 1]);
        }

        // ---- state update (registers only) ----
        #pragma unroll
        for (int rt = 0; rt < 2; ++rt)
            #pragma unroll
            for (int fc = 0; fc < 4; ++fc)
                state[rt][fc] = acc2[rt][fc];

        if (k < NL - 1) {
            // prefetch next layer's chunks 0..3 (slots 0..3 free after p=15)
            stage32(WFk + WF_LAYER, B_lds, 0, w, lane);
            stage32(WFk + WF_LAYER, B_lds, 1, w, lane);
            stage32(WFk + WF_LAYER, B_lds, 2, w, lane);
            stage32(WFk + WF_LAYER, B_lds, 3, w, lane);

            // waves 0-3: publish bf16 H to global (halo) + LDS tap1 (center)
            if (w < 4) {
                #pragma unroll
                for (int rt = 0; rt < 2; ++rt)
                    #pragma unroll
                    for (int fc = 0; fc < 4; ++fc)
                        #pragma unroll
                        for (int i = 0; i < 4; ++i) {
                            const int row = rt * 16 + krow * 4 + i;
                            const int col = c0 + fc * 16 + arow;
                            const unsigned short hb = f2bf(state[rt][fc][i]);
                            Hb_out[((j0 + row) << 8) + col] = hb;
                            A_lds[((32 + row) << 8) + (((col << 1) ^ ((row & 7) << 4)) >> 1)] = hb;
                        }
            }
            target += NBLK;
            grid_barrier(counter, target, tid);   // drains prefetch + publishes H

            unsigned short* tmp = (unsigned short*)Hb_in;
            Hb_in = Hb_out; Hb_out = tmp;
        } else {
            // last layer: S (waves 4-7) -> tap0 bf16 for the final GEMM
            LGKM0(); SBAR();   // all phase-2 tap0 reads done
            if (w >= 4) {
                #pragma unroll
                for (int rt = 0; rt < 2; ++rt)
                    #pragma unroll
                    for (int fc = 0; fc < 4; ++fc)
                        #pragma unroll
                        for (int i = 0; i < 4; ++i) {
                            const int row = rt * 16 + krow * 4 + i;
                            const int col = cs0 + fc * 16 + arow;
                            A_lds[(row << 8) + (((col << 1) ^ ((row & 7) << 4)) >> 1)] =
                                f2bf(state[rt][fc][i]);
                        }
            }
            LGKM0(); SBAR();
        }
    }

    // ================= final: out = Wfb @ S^T + fbias =======================
    {
        const int m0 = w * 32;   // co slice
        f32x4 facc[2][2];
        #pragma unroll
        for (int rt = 0; rt < 2; ++rt)
            #pragma unroll
            for (int fc = 0; fc < 2; ++fc)
                facc[rt][fc] = (f32x4){0.f, 0.f, 0.f, 0.f};

        #pragma unroll
        for (int kc = 0; kc < 8; ++kc) {
            const int koff = kc * 32 + krow * 8;
            const bf16x8 a0 = *(const bf16x8*)(Wfb + ((m0 + arow) << 8) + koff);
            const bf16x8 a1 = *(const bf16x8*)(Wfb + ((m0 + 16 + arow) << 8) + koff);
            const int aoff = ((kc * 64 + krow * 16) ^ aswz) >> 1;
            const bf16x8 b0 = *(const bf16x8*)(A_lds + (arow << 8) + aoff);
            const bf16x8 b1 = *(const bf16x8*)(A_lds + ((16 + arow) << 8) + aoff);
            facc[0][0] = MFMA16(a0, b0, facc[0][0]);
            facc[1][0] = MFMA16(a1, b0, facc[1][0]);
            facc[0][1] = MFMA16(a0, b1, facc[0][1]);
            facc[1][1] = MFMA16(a1, b1, facc[1][1]);
        }

        #pragma unroll
        for (int rt = 0; rt < 2; ++rt)
            #pragma unroll
            for (int fc = 0; fc < 2; ++fc)
                #pragma unroll
                for (int i = 0; i < 4; ++i) {
                    const int co = m0 + rt * 16 + krow * 4 + i;
                    const int jj = j0 + fc * 16 + arow;
                    out[((jj & 1) << 20) + (co << 12) + (jj >> 1)] = facc[rt][fc][i] + fbias[co];
                }
    }
}

// ---------------------------------------------------------------------------
extern "C" void kernel_launch(void* const* d_in, const int* in_sizes, int n_in,
                              void* d_out, int out_size, void* d_ws, size_t ws_size,
                              hipStream_t stream)
{
    const float* x       = (const float*)d_in[0];
    const float* init_w  = (const float*)d_in[1];
    const float* init_b  = (const float*)d_in[2];
    const float* iskip_w = (const float*)d_in[3];
    const float* iskip_b = (const float*)d_in[4];
    const float* gate_w  = (const float*)d_in[5];
    const float* gate_b  = (const float*)d_in[6];
    const float* feat_w  = (const float*)d_in[7];
    const float* feat_b  = (const float*)d_in[8];
    const float* skip_w  = (const float*)d_in[9];
    const float* thru_w  = (const float*)d_in[10];
    const float* final_w = (const float*)d_in[11];
    const float* final_b = (const float*)d_in[12];

    char* ws = (char*)d_ws;
    size_t off = 0;
    auto alloc = [&](size_t bytes) {
        void* p = ws + off;
        off += (bytes + 255) & ~(size_t)255;
        return p;
    };
    unsigned short* WF  = (unsigned short*)alloc((size_t)NL * WF_LAYER * 2);
    unsigned short* Wib = (unsigned short*)alloc(256 * 256 * 2);
    unsigned short* Wfb = (unsigned short*)alloc(256 * 256 * 2);
    unsigned short* Hb0 = (unsigned short*)alloc((size_t)TS * 256 * 2);
    unsigned short* Hb1 = (unsigned short*)alloc((size_t)TS * 256 * 2);
    unsigned*       cnt = (unsigned*)alloc(256);

    hipMemsetAsync((void*)cnt, 0, 256, stream);
    prep_weights_kernel<<<2048, 256, 0, stream>>>(gate_w, feat_w, thru_w, skip_w,
                                                  iskip_w, final_w, WF, Wib, Wfb);
    wavenet_kernel<<<NBLK, 512, 0, stream>>>(
        x, init_w, init_b, Wib, iskip_b, WF, gate_b, feat_b,
        Wfb, final_b, Hb0, Hb1, (float*)d_out, cnt);
}